// Round 9
// baseline (416.844 us; speedup 1.0000x reference)
//
#include <hip/hip_runtime.h>
#include <math.h>

#define NODES 100000
#define EDGES 1600000
#define NBUCK 196     // ceil(NODES/512) dst-range buckets (512 nodes each)
#define BCAP2 12288   // capacity per bucket (mean 8163, +45 sigma slack)
#define EPB 4096      // edges per binning block
#define BINB 391      // ceil(EDGES/EPB)
#define GEMMB 1563    // ceil((NODES/16)/4)
#define AGG_BLK 2048  // persistent agg blocks (8/CU); tiles beyond stolen via counter
#define FIN_WAVES (AGG_BLK * 4)

typedef __attribute__((ext_vector_type(8))) short short8;
typedef __attribute__((ext_vector_type(4))) float floatx4;
typedef __attribute__((ext_vector_type(4))) unsigned uv4;

// group-of-8 reduction (xor 4,2,1 stays inside an aligned 8-lane group)
__device__ __forceinline__ float gsum8(float x) {
#pragma unroll
  for (int o = 4; o > 0; o >>= 1) x += __shfl_xor(x, o, 64);
  return x;
}

// bf16 <-> fp32 (RNE), no dependence on __hip_bfloat16 internals.
__device__ __forceinline__ short f2bf(float f) {
  union { float f; unsigned u; } v;
  v.f = f;
  unsigned r = 0x7fffu + ((v.u >> 16) & 1u);
  return (short)((v.u + r) >> 16);
}
__device__ __forceinline__ float bflo(unsigned p) {
  union { unsigned u; float f; } v; v.u = p << 16; return v.f;
}
__device__ __forceinline__ float bfhi(unsigned p) {
  union { unsigned u; float f; } v; v.u = p & 0xffff0000u; return v.f;
}

// ---------- phase A body: LDS-staged binning with COALESCED bin writes ----------
// record = src (17b) | (dst & 511) << 17
#define BIN_SMEM (4 * 256 * 4 + EPB * 4 + EPB)
__device__ __forceinline__ void bin_body(char* smemraw, int b, const int* __restrict__ src,
                                         const int* __restrict__ dst, int* __restrict__ bins,
                                         int* __restrict__ gcur) {
  int* cnt = (int*)smemraw;            // 256
  int* gb = cnt + 256;                 // 256
  int* lb = gb + 256;                  // 256 (scan / exclusive base)
  int* lcur = lb + 256;                // 256
  int* rec = lcur + 256;               // EPB records
  unsigned char* rbk = (unsigned char*)(rec + EPB);  // EPB bucket ids
  int t = threadIdx.x;
  cnt[t] = 0;
  __syncthreads();
  int base = b * EPB;
  int nv = EDGES - base; if (nv > EPB) nv = EPB;
  int s[16], d[16];
#pragma unroll
  for (int j = 0; j < 16; ++j) {
    int e = base + j * 256 + t;  // coalesced
    if (e < EDGES) {
      s[j] = src[e];
      d[j] = dst[e];
      atomicAdd(&cnt[d[j] >> 9], 1);
    } else {
      d[j] = -1;
    }
  }
  __syncthreads();
  // block-local exclusive scan of bucket counts
  int c = cnt[t];
  lb[t] = c;
  __syncthreads();
  for (int o = 1; o < 256; o <<= 1) {
    int u = (t >= o) ? lb[t - o] : 0;
    __syncthreads();
    lb[t] += u;
    __syncthreads();
  }
  int ex = lb[t] - c;  // exclusive local base of bucket t
  gb[t] = (c > 0) ? atomicAdd(&gcur[t], c) : 0;  // ONE global atomic per (block,bucket)
  __syncthreads();
  lb[t] = ex;
  lcur[t] = ex;
  __syncthreads();
  // counting-sort records into LDS (bucket-contiguous)
#pragma unroll
  for (int j = 0; j < 16; ++j) {
    if (d[j] >= 0) {
      int bk = d[j] >> 9;
      int lp = atomicAdd(&lcur[bk], 1);  // LDS atomic (cheap)
      rec[lp] = s[j] | ((d[j] & 511) << 17);
      rbk[lp] = (unsigned char)bk;
    }
  }
  __syncthreads();
  // coalesced copy-out: consecutive i within a bucket -> consecutive global addresses
  for (int i = t; i < nv; i += 256) {
    int bk = rbk[i];
    int pos = gb[bk] + (i - lb[bk]);
    if (pos < BCAP2) bins[bk * BCAP2 + pos] = rec[i];
  }
}

// ---------- fill: bucket scan + histogram + rowptr/dinv + LDS-staged COALESCED csr ----------
#define FILL_SMEM (256 * 4 + 512 * 4 + 512 * 4 + 4 * 4 + BCAP2 * 4)
__device__ __forceinline__ void fill_body(char* smemraw, int b, const int* __restrict__ bins,
                                          const int* __restrict__ gcur, int* __restrict__ rowptr,
                                          float* __restrict__ dinv, int* __restrict__ csr,
                                          int* __restrict__ wctr) {
  int* bsm = (int*)smemraw;   // 256 ints
  int* cnt = bsm + 256;       // 512
  int* cur = cnt + 512;       // 512
  int* wtot = cur + 512;      // 4
  int* stage = wtot + 4;      // BCAP2
  int t = threadIdx.x;
  if (t < 4) wctr[t] = 0;     // zero work-steal counters for the agg kernels
  int v = 0;
  if (t < NBUCK) { v = gcur[t]; if (v > BCAP2) v = BCAP2; }
  bsm[t] = v;
  cnt[t] = 0; cnt[t + 256] = 0;
  __syncthreads();
  for (int o = 1; o < 256; o <<= 1) {
    int u = (t >= o) ? bsm[t - o] : 0;
    __syncthreads();
    bsm[t] += u;
    __syncthreads();
  }
  if (b == 0 && t == NBUCK - 1) rowptr[NODES] = bsm[t];  // total placed
  int cb = gcur[b]; if (cb > BCAP2) cb = BCAP2;
  int bbase = bsm[b] - cb;  // exclusive global bucket base
  const int* bp = &bins[(size_t)b * BCAP2];
  for (int i = t; i < cb; i += 256)
    atomicAdd(&cnt[(bp[i] >> 17) & 511], 1);
  __syncthreads();
  int a0 = cnt[2 * t], a1 = cnt[2 * t + 1];
  int sum2 = a0 + a1;
  int lane = t & 63, w = t >> 6;
  int inc = sum2;
#pragma unroll
  for (int o = 1; o < 64; o <<= 1) {
    int u = __shfl_up(inc, o, 64);
    if (lane >= o) inc += u;
  }
  if (lane == 63) wtot[w] = inc;
  __syncthreads();
  int wpre = 0;
  for (int ww = 0; ww < w; ++ww) wpre += wtot[ww];
  int l0 = wpre + inc - sum2;   // LOCAL exclusive offset of node 2t within bucket
  int l1 = l0 + a0;
  int n0 = b * 512 + 2 * t, n1 = n0 + 1;
  if (n0 < NODES) { rowptr[n0] = bbase + l0; dinv[n0] = rsqrtf((float)a0 + 1.0f); }
  if (n1 < NODES) { rowptr[n1] = bbase + l1; dinv[n1] = rsqrtf((float)a1 + 1.0f); }
  cur[2 * t] = l0; cur[2 * t + 1] = l1;   // LOCAL positions -> stage in LDS
  __syncthreads();
  for (int i = t; i < cb; i += 256) {
    int pk = bp[i];
    int lp = atomicAdd(&cur[(pk >> 17) & 511], 1);
    stage[lp] = pk & 0x1FFFF;
  }
  __syncthreads();
  // fully coalesced csr write-out
  for (int i = t; i < cb; i += 256) csr[bbase + i] = stage[i];
}

// ---------- GEMM body: [N,128] fp32 @ [128,64] -> hs = bf16(x@W) (UNscaled) ----------
#define GEMM_SMEM (64 * 136 * 2)
__device__ __forceinline__ void gemm_body(char* smemraw, int tile0, const float* __restrict__ x,
                                          const float* __restrict__ W, short* __restrict__ hs) {
  constexpr int K = 128, KP = K + 8;
  short* wt = (short*)smemraw;  // W^T staged as bf16
  for (int idx = threadIdx.x; idx < K * 64; idx += 256) {
    int k = idx >> 6, n = idx & 63;
    wt[n * KP + k] = f2bf(W[idx]);
  }
  __syncthreads();
  int wid = threadIdx.x >> 6, lane = threadIdx.x & 63;
  int tile = tile0 + wid;
  if (tile * 16 >= NODES) return;
  int m = lane & 15, q = lane >> 4;

  short8 bfr[4][K / 32];
#pragma unroll
  for (int ct = 0; ct < 4; ++ct)
#pragma unroll
    for (int ks = 0; ks < K / 32; ++ks)
      bfr[ct][ks] = *reinterpret_cast<const short8*>(&wt[(ct * 16 + m) * KP + ks * 32 + q * 8]);

  floatx4 acc[4];
#pragma unroll
  for (int ct = 0; ct < 4; ++ct) acc[ct] = {0.f, 0.f, 0.f, 0.f};
  int r0 = tile * 16;
#pragma unroll
  for (int ks = 0; ks < K / 32; ++ks) {
    const float* xp = &x[(size_t)(r0 + m) * K + ks * 32 + q * 8];
    floatx4 a0 = *reinterpret_cast<const floatx4*>(xp);
    floatx4 a1 = *reinterpret_cast<const floatx4*>(xp + 4);
    short8 af;
#pragma unroll
    for (int j = 0; j < 4; ++j) { af[j] = f2bf(a0[j]); af[4 + j] = f2bf(a1[j]); }
#pragma unroll
    for (int ct = 0; ct < 4; ++ct)
      acc[ct] = __builtin_amdgcn_mfma_f32_16x16x32_bf16(af, bfr[ct][ks], acc[ct], 0, 0, 0);
  }
  // C/D: col = lane&15, row = (lane>>4)*4 + reg   [measured m89/m91]
#pragma unroll
  for (int ct = 0; ct < 4; ++ct)
#pragma unroll
    for (int r = 0; r < 4; ++r) {
      int row = r0 + q * 4 + r, col = ct * 16 + m;
      hs[row * 64 + col] = f2bf(acc[ct][r]);
    }
}

// ---------- ROUND-0 aggregation loop, weight-parameterized ----------
// acc = [PRESCALED ? 1 : dn]*hs[n] + sum_j w_j * hs[src_j],  w_j = PRESCALED?1:dinv[src_j]
template <bool PRESCALED>
__device__ __forceinline__ void do_agg(const uv4* __restrict__ hsv, const float* __restrict__ dinv,
                                       const int* __restrict__ csr, int n, int e0, int e1,
                                       int lane, float dn, float acc[8]) {
  int q = lane & 7, srcb = lane & 0x38;
  uv4 sv = hsv[(size_t)n * 8 + q];  // self row, features q*8..q*8+7
#pragma unroll
  for (int w = 0; w < 4; ++w) {
    float lo = bflo(sv[w]), hi = bfhi(sv[w]);
    if constexpr (PRESCALED) { acc[2 * w] = lo; acc[2 * w + 1] = hi; }
    else { acc[2 * w] = lo * dn; acc[2 * w + 1] = hi * dn; }
  }
  for (int base = e0; base < e1; base += 8) {
    int cnt = e1 - base;
    if (cnt > 8) cnt = 8;
    int a = base + (q < cnt ? q : 0);       // clamp: always valid in-row index
    int sidx = csr[a];
    float gq = 1.0f;
    if constexpr (!PRESCALED) gq = dinv[sidx];
    int s[8]; float wj[8];
#pragma unroll
    for (int j = 0; j < 8; ++j) {
      s[j] = __shfl(sidx, srcb | j, 64);
      if constexpr (!PRESCALED) {
        float bj = __shfl(gq, srcb | j, 64);
        wj[j] = (j < cnt) ? bj : 0.0f;
      } else {
        wj[j] = 1.0f;  // unused in PRESCALED accumulate below
      }
    }
    uv4 v[8];
#pragma unroll
    for (int j = 0; j < 8; ++j) v[j] = hsv[(size_t)s[j] * 8 + q];
    if constexpr (PRESCALED) {
      if (cnt == 8) {
#pragma unroll
        for (int j = 0; j < 8; ++j)
#pragma unroll
          for (int w = 0; w < 4; ++w) { acc[2 * w] += bflo(v[j][w]); acc[2 * w + 1] += bfhi(v[j][w]); }
      } else {
#pragma unroll
        for (int j = 0; j < 8; ++j)
          if (j < cnt)
#pragma unroll
            for (int w = 0; w < 4; ++w) { acc[2 * w] += bflo(v[j][w]); acc[2 * w + 1] += bfhi(v[j][w]); }
      }
    } else {
#pragma unroll
      for (int j = 0; j < 8; ++j)
#pragma unroll
        for (int w = 0; w < 4; ++w) {
          acc[2 * w]     += wj[j] * bflo(v[j][w]);
          acc[2 * w + 1] += wj[j] * bfhi(v[j][w]);
        }
    }
  }
}

// ---------- fused aggregate + bias + LN + GELU + next-layer GEMM ----------
// Persistent blocks: first tile = blockIdx, rest stolen via atomic counter (tail balance).
// W staged IN-KERNEL from fp32 once per persistent block (round-6 proven context).
// writes hsn = dinv ⊙ (u @ W)  [row-scale commute]
template <bool PRESCALED>
__global__ __launch_bounds__(256) void k_aggg(const short* __restrict__ hs,
                                              const float* __restrict__ dinv,
                                              const int* __restrict__ rowptr,
                                              const int* __restrict__ csr,
                                              const float* __restrict__ bias,
                                              const float* __restrict__ gam,
                                              const float* __restrict__ bet,
                                              const float* __restrict__ W,   // next-layer W fp32 [64x64]
                                              short* __restrict__ hsn,
                                              int* __restrict__ ctr) {
  __shared__ __align__(16) short wt[64 * 72];  // W^T bf16
  __shared__ __align__(16) short ut[32 * 72];  // (dinv*u) tile bf16
  __shared__ int tile_s;
  int t = threadIdx.x;
  for (int idx = t; idx < 4096; idx += 256) {
    int k = idx >> 6, n = idx & 63;
    wt[n * 72 + k] = f2bf(W[idx]);
  }
  const uv4* hsv = (const uv4*)hs;
  int lane = t & 63, wid = t >> 6;
  int g = lane >> 3, q = lane & 7;
  int tile = blockIdx.x;                      // static first tile: no grab burst
  while (tile < NODES / 32) {
    int nb0 = tile * 32;
    int r = wid * 8 + g;                      // row in 32-node tile
    int n = nb0 + r;
    int e0 = rowptr[n], e1 = rowptr[n + 1];
    float dn = dinv[n];
    float acc[8];
    do_agg<PRESCALED>(hsv, dinv, csr, n, e0, e1, lane, dn, acc);

    const floatx4* bi4 = (const floatx4*)bias;
    floatx4 b0 = bi4[q * 2], b1 = bi4[q * 2 + 1];
#pragma unroll
    for (int f = 0; f < 4; ++f) { acc[f] = acc[f] * dn + b0[f]; acc[f + 4] = acc[f + 4] * dn + b1[f]; }

    float lsum = 0.f;
#pragma unroll
    for (int f = 0; f < 8; ++f) lsum += acc[f];
    float mu = gsum8(lsum) * (1.0f / 64.0f);
    float d[8], lvar = 0.f;
#pragma unroll
    for (int f = 0; f < 8; ++f) { d[f] = acc[f] - mu; lvar += d[f] * d[f]; }
    float rs = rsqrtf(gsum8(lvar) * (1.0f / 64.0f) + 1e-5f);
    const floatx4* gm4 = (const floatx4*)gam;
    const floatx4* bt4 = (const floatx4*)bet;
    floatx4 g0 = gm4[q * 2], g1 = gm4[q * 2 + 1];
    floatx4 t0 = bt4[q * 2], t1 = bt4[q * 2 + 1];
    short8 us;
#pragma unroll
    for (int f = 0; f < 8; ++f) {
      float gv = (f < 4) ? g0[f] : g1[f - 4];
      float tv = (f < 4) ? t0[f] : t1[f - 4];
      float vv = d[f] * rs * gv + tv;
      float u = 0.5f * vv * (1.0f + erff(vv * 0.70710678118654752f));  // exact GELU
      us[f] = f2bf(u * dn);                   // prescale for next layer (commute)
    }
    *reinterpret_cast<short8*>(&ut[r * 72 + q * 8]) = us;
    __syncthreads();

    // in-block GEMM: 32x64 tile @ W (64x64) -> hsn rows nb0..nb0+31
    int m = lane & 15, q2 = lane >> 4;
    int tl = wid >> 1, cb = (wid & 1) * 2;    // wave -> (row-tile, ct pair)
    short8 bfr[2][2];
#pragma unroll
    for (int ct = 0; ct < 2; ++ct)
#pragma unroll
      for (int ks = 0; ks < 2; ++ks)
        bfr[ct][ks] = *reinterpret_cast<const short8*>(&wt[((cb + ct) * 16 + m) * 72 + ks * 32 + q2 * 8]);
    floatx4 ac[2];
#pragma unroll
    for (int ct = 0; ct < 2; ++ct) ac[ct] = {0.f, 0.f, 0.f, 0.f};
#pragma unroll
    for (int ks = 0; ks < 2; ++ks) {
      short8 af = *reinterpret_cast<const short8*>(&ut[(tl * 16 + m) * 72 + ks * 32 + q2 * 8]);
#pragma unroll
      for (int ct = 0; ct < 2; ++ct)
        ac[ct] = __builtin_amdgcn_mfma_f32_16x16x32_bf16(af, bfr[ct][ks], ac[ct], 0, 0, 0);
    }
#pragma unroll
    for (int ct = 0; ct < 2; ++ct)
#pragma unroll
      for (int rr = 0; rr < 4; ++rr) {
        int row = nb0 + tl * 16 + q2 * 4 + rr, col = (cb + ct) * 16 + m;
        hsn[row * 64 + col] = f2bf(ac[ct][rr]);
      }
    // steal next tile (only ~1077 grabs total, spread over runtime)
    if (t == 0) tile_s = atomicAdd(ctr, 1);
    __syncthreads();                          // orders tile_s read + ut WAR
    tile = AGG_BLK + tile_s;
  }
}

// ---------- final layer: aggregate + bias + LN + GELU + head (per-wave stealing) ----------
__global__ __launch_bounds__(256) void k_agg_fin(const short* __restrict__ hs,
                                                 const float* __restrict__ dinv,
                                                 const int* __restrict__ rowptr,
                                                 const int* __restrict__ csr,
                                                 const float* __restrict__ bias,
                                                 const float* __restrict__ gam,
                                                 const float* __restrict__ bet,
                                                 const float* __restrict__ Wh,
                                                 const float* __restrict__ bh,
                                                 float* __restrict__ out,
                                                 int* __restrict__ ctr) {
  const uv4* hsv = (const uv4*)hs;
  int lane = threadIdx.x & 63, wid = threadIdx.x >> 6;
  int g = lane >> 3, q = lane & 7;
  int ch = blockIdx.x * 4 + wid;              // wave-chunk = 8 nodes; static first chunk
  while (ch < NODES / 8) {
    int n = ch * 8 + g;
    int e0 = rowptr[n], e1 = rowptr[n + 1];
    float dn = dinv[n];
    float acc[8];
    do_agg<true>(hsv, dinv, csr, n, e0, e1, lane, dn, acc);
    const floatx4* bi4 = (const floatx4*)bias;
    floatx4 b0 = bi4[q * 2], b1 = bi4[q * 2 + 1];
#pragma unroll
    for (int f = 0; f < 4; ++f) { acc[f] = acc[f] * dn + b0[f]; acc[f + 4] = acc[f + 4] * dn + b1[f]; }
    float lsum = 0.f;
#pragma unroll
    for (int f = 0; f < 8; ++f) lsum += acc[f];
    float mu = gsum8(lsum) * (1.0f / 64.0f);
    float d[8], lvar = 0.f;
#pragma unroll
    for (int f = 0; f < 8; ++f) { d[f] = acc[f] - mu; lvar += d[f] * d[f]; }
    float rs = rsqrtf(gsum8(lvar) * (1.0f / 64.0f) + 1e-5f);
    const floatx4* gm4 = (const floatx4*)gam;
    const floatx4* bt4 = (const floatx4*)bet;
    floatx4 g0 = gm4[q * 2], g1 = gm4[q * 2 + 1];
    floatx4 t0 = bt4[q * 2], t1 = bt4[q * 2 + 1];
    const floatx4* wh4 = (const floatx4*)Wh;
    floatx4 w0 = wh4[q * 2], w1 = wh4[q * 2 + 1];
    float lp = 0.f;
#pragma unroll
    for (int f = 0; f < 8; ++f) {
      float gv = (f < 4) ? g0[f] : g1[f - 4];
      float tv = (f < 4) ? t0[f] : t1[f - 4];
      float wv = (f < 4) ? w0[f] : w1[f - 4];
      float vv = d[f] * rs * gv + tv;
      float u = 0.5f * vv * (1.0f + erff(vv * 0.70710678118654752f));
      lp += u * wv;
    }
    float p = gsum8(lp);
    if (q == 0) out[n] = p + bh[0];
    int nx;
    if (lane == 0) nx = atomicAdd(ctr, 1);
    ch = FIN_WAVES + __shfl(nx, 0, 64);
  }
}

// ---------- fused dispatch wrappers ----------
// dispatch 1: binning (391) || FULL gemm (1563)
__global__ __launch_bounds__(256) void k_pre1(const int* __restrict__ src, const int* __restrict__ dst,
                                              int* __restrict__ bins, int* __restrict__ gcur,
                                              const float* __restrict__ x, const float* __restrict__ W1,
                                              short* __restrict__ hs) {
  __shared__ __align__(16) char smem[BIN_SMEM];  // 24576 >= GEMM_SMEM 17408
  int b = blockIdx.x;
  if (b < BINB) bin_body(smem, b, src, dst, bins, gcur);
  else gemm_body(smem, (b - BINB) * 4, x, W1, hs);
}

// dispatch 2: csr fill (196 blocks, big LDS stage)
__global__ __launch_bounds__(256) void k_pre2(const int* __restrict__ bins, const int* __restrict__ gcur,
                                              int* __restrict__ rowptr, float* __restrict__ dinv,
                                              int* __restrict__ csr, int* __restrict__ wctr) {
  __shared__ __align__(16) char smem[FILL_SMEM];
  fill_body(smem, blockIdx.x, bins, gcur, rowptr, dinv, csr, wctr);
}

// standalone fallback wrappers (ws too small to un-alias bins)
__global__ __launch_bounds__(256) void k_bin2(const int* src, const int* dst, int* bins, int* gcur) {
  __shared__ __align__(16) char smem[BIN_SMEM];
  bin_body(smem, blockIdx.x, src, dst, bins, gcur);
}
__global__ __launch_bounds__(256) void k_fillb2(const int* bins, const int* gcur, int* rowptr,
                                                float* dinv, int* csr, int* wctr) {
  __shared__ __align__(16) char smem[FILL_SMEM];
  fill_body(smem, blockIdx.x, bins, gcur, rowptr, dinv, csr, wctr);
}
__global__ __launch_bounds__(256) void k_gemm(const float* x, const float* W, short* hs) {
  __shared__ __align__(16) char smem[GEMM_SMEM];
  gemm_body(smem, blockIdx.x * 4, x, W, hs);
}

extern "C" void kernel_launch(void* const* d_in, const int* in_sizes, int n_in,
                              void* d_out, int out_size, void* d_ws, size_t ws_size,
                              hipStream_t stream) {
  const float* x  = (const float*)d_in[0];
  const int* ei   = (const int*)d_in[1];
  const float* W1 = (const float*)d_in[2];
  const float* b1 = (const float*)d_in[3];
  const float* g1 = (const float*)d_in[4];
  const float* be1= (const float*)d_in[5];
  const float* W2 = (const float*)d_in[6];
  const float* b2 = (const float*)d_in[7];
  const float* g2 = (const float*)d_in[8];
  const float* be2= (const float*)d_in[9];
  const float* W3 = (const float*)d_in[10];
  const float* b3 = (const float*)d_in[11];
  const float* g3 = (const float*)d_in[12];
  const float* be3= (const float*)d_in[13];
  const float* Wh = (const float*)d_in[14];
  const float* bh = (const float*)d_in[15];
  const int* srcp = ei;
  const int* dstp = ei + EDGES;

  char* ws = (char*)d_ws;
  size_t off = 0;
  auto take = [&](size_t bytes) {
    char* p = ws + off;
    off = (off + bytes + 255) & ~(size_t)255;
    return p;
  };
  float* dinv = (float*)take((size_t)NODES * 4);
  int* rowptr = (int*)take((size_t)(NODES + 1) * 4);
  int* csr    = (int*)take((size_t)EDGES * 4);
  int* wctr   = (int*)take(256);                        // work-steal counters (zeroed by fill)
  short* hs_a = (short*)take((size_t)NODES * 64 * 2);   // 12.8 MB
  short* hs_b = (short*)take((size_t)NODES * 64 * 2);   // 12.8 MB

  size_t bins_sz = (size_t)NBUCK * BCAP2 * 4;           // 9.63 MB
  bool overlap = (ws_size >= off + bins_sz + 4096);
  int* bins; int* gcur;
  if (overlap) {
    bins = (int*)take(bins_sz);
    gcur = (int*)take((size_t)NBUCK * 4);
  } else {
    // fall back to aliasing (bins consumed by fill before any GEMM writes hs)
    bins = (int*)hs_a;
    gcur = (int*)hs_b;
  }

  (void)hipMemsetAsync(gcur, 0, (size_t)NBUCK * 4, stream);
  if (overlap) {
    k_pre1<<<BINB + GEMMB, 256, 0, stream>>>(srcp, dstp, bins, gcur, x, W1, hs_a);
    k_pre2<<<NBUCK, 256, 0, stream>>>(bins, gcur, rowptr, dinv, csr, wctr);
  } else {
    k_bin2<<<BINB, 256, 0, stream>>>(srcp, dstp, bins, gcur);
    k_fillb2<<<NBUCK, 256, 0, stream>>>(bins, gcur, rowptr, dinv, csr, wctr);
    k_gemm<<<GEMMB, 256, 0, stream>>>(x, W1, hs_a);
  }
  // layer 1: hs_a is UNscaled -> gather dinv[src] per edge (weights in agg)
  k_aggg<false><<<AGG_BLK, 256, 0, stream>>>(hs_a, dinv, rowptr, csr, b1, g1, be1, W2, hs_b, wctr + 0);
  // layers 2/3: producer prescaled rows by dinv
  k_aggg<true><<<AGG_BLK, 256, 0, stream>>>(hs_b, dinv, rowptr, csr, b2, g2, be2, W3, hs_a, wctr + 1);
  k_agg_fin<<<AGG_BLK, 256, 0, stream>>>(hs_a, dinv, rowptr, csr, b3, g3, be3, Wh, bh, (float*)d_out, wctr + 2);
}

// Round 10
// 264.523 us; speedup vs baseline: 1.5758x; 1.5758x over previous
//
#include <hip/hip_runtime.h>
#include <math.h>

#define NODES 100000
#define EDGES 1600000
#define NBUCK 196     // ceil(NODES/512) dst-range buckets (512 nodes each)
#define BCAP2 12288   // capacity per bucket (mean 8163, +45 sigma slack)
#define EPB 4096      // edges per binning block
#define BINB 391      // ceil(EDGES/EPB)
#define GEMMB 1563    // ceil((NODES/16)/4)

typedef __attribute__((ext_vector_type(8))) short short8;
typedef __attribute__((ext_vector_type(4))) float floatx4;
typedef __attribute__((ext_vector_type(4))) unsigned uv4;

// group-of-8 reduction (xor 4,2,1 stays inside an aligned 8-lane group)
__device__ __forceinline__ float gsum8(float x) {
#pragma unroll
  for (int o = 4; o > 0; o >>= 1) x += __shfl_xor(x, o, 64);
  return x;
}

// bf16 <-> fp32 (RNE), no dependence on __hip_bfloat16 internals.
__device__ __forceinline__ short f2bf(float f) {
  union { float f; unsigned u; } v;
  v.f = f;
  unsigned r = 0x7fffu + ((v.u >> 16) & 1u);
  return (short)((v.u + r) >> 16);
}
__device__ __forceinline__ float bflo(unsigned p) {
  union { unsigned u; float f; } v; v.u = p << 16; return v.f;
}
__device__ __forceinline__ float bfhi(unsigned p) {
  union { unsigned u; float f; } v; v.u = p & 0xffff0000u; return v.f;
}

// ---------- phase A body: LDS-staged binning with COALESCED bin writes ----------
// record = src (17b) | (dst & 511) << 17
#define BIN_SMEM (4 * 256 * 4 + EPB * 4 + EPB)
__device__ __forceinline__ void bin_body(char* smemraw, int b, const int* __restrict__ src,
                                         const int* __restrict__ dst, int* __restrict__ bins,
                                         int* __restrict__ gcur) {
  int* cnt = (int*)smemraw;            // 256
  int* gb = cnt + 256;                 // 256
  int* lb = gb + 256;                  // 256 (scan / exclusive base)
  int* lcur = lb + 256;                // 256
  int* rec = lcur + 256;               // EPB records
  unsigned char* rbk = (unsigned char*)(rec + EPB);  // EPB bucket ids
  int t = threadIdx.x;
  cnt[t] = 0;
  __syncthreads();
  int base = b * EPB;
  int nv = EDGES - base; if (nv > EPB) nv = EPB;
  int s[16], d[16];
#pragma unroll
  for (int j = 0; j < 16; ++j) {
    int e = base + j * 256 + t;  // coalesced
    if (e < EDGES) {
      s[j] = src[e];
      d[j] = dst[e];
      atomicAdd(&cnt[d[j] >> 9], 1);
    } else {
      d[j] = -1;
    }
  }
  __syncthreads();
  // block-local exclusive scan of bucket counts
  int c = cnt[t];
  lb[t] = c;
  __syncthreads();
  for (int o = 1; o < 256; o <<= 1) {
    int u = (t >= o) ? lb[t - o] : 0;
    __syncthreads();
    lb[t] += u;
    __syncthreads();
  }
  int ex = lb[t] - c;  // exclusive local base of bucket t
  gb[t] = (c > 0) ? atomicAdd(&gcur[t], c) : 0;  // ONE global atomic per (block,bucket)
  __syncthreads();
  lb[t] = ex;
  lcur[t] = ex;
  __syncthreads();
  // counting-sort records into LDS (bucket-contiguous)
#pragma unroll
  for (int j = 0; j < 16; ++j) {
    if (d[j] >= 0) {
      int bk = d[j] >> 9;
      int lp = atomicAdd(&lcur[bk], 1);  // LDS atomic (cheap)
      rec[lp] = s[j] | ((d[j] & 511) << 17);
      rbk[lp] = (unsigned char)bk;
    }
  }
  __syncthreads();
  // coalesced copy-out: consecutive i within a bucket -> consecutive global addresses
  for (int i = t; i < nv; i += 256) {
    int bk = rbk[i];
    int pos = gb[bk] + (i - lb[bk]);
    if (pos < BCAP2) bins[bk * BCAP2 + pos] = rec[i];
  }
}

// ---------- fill: bucket scan + histogram + rowptr/dinv + LDS-staged COALESCED csr ----------
#define FILL_SMEM (256 * 4 + 512 * 4 + 512 * 4 + 4 * 4 + BCAP2 * 4)
__device__ __forceinline__ void fill_body(char* smemraw, int b, const int* __restrict__ bins,
                                          const int* __restrict__ gcur, int* __restrict__ rowptr,
                                          float* __restrict__ dinv, int* __restrict__ csr) {
  int* bsm = (int*)smemraw;   // 256 ints
  int* cnt = bsm + 256;       // 512
  int* cur = cnt + 512;       // 512
  int* wtot = cur + 512;      // 4
  int* stage = wtot + 4;      // BCAP2
  int t = threadIdx.x;
  int v = 0;
  if (t < NBUCK) { v = gcur[t]; if (v > BCAP2) v = BCAP2; }
  bsm[t] = v;
  cnt[t] = 0; cnt[t + 256] = 0;
  __syncthreads();
  for (int o = 1; o < 256; o <<= 1) {
    int u = (t >= o) ? bsm[t - o] : 0;
    __syncthreads();
    bsm[t] += u;
    __syncthreads();
  }
  if (b == 0 && t == NBUCK - 1) rowptr[NODES] = bsm[t];  // total placed
  int cb = gcur[b]; if (cb > BCAP2) cb = BCAP2;
  int bbase = bsm[b] - cb;  // exclusive global bucket base
  const int* bp = &bins[(size_t)b * BCAP2];
  for (int i = t; i < cb; i += 256)
    atomicAdd(&cnt[(bp[i] >> 17) & 511], 1);
  __syncthreads();
  int a0 = cnt[2 * t], a1 = cnt[2 * t + 1];
  int sum2 = a0 + a1;
  int lane = t & 63, w = t >> 6;
  int inc = sum2;
#pragma unroll
  for (int o = 1; o < 64; o <<= 1) {
    int u = __shfl_up(inc, o, 64);
    if (lane >= o) inc += u;
  }
  if (lane == 63) wtot[w] = inc;
  __syncthreads();
  int wpre = 0;
  for (int ww = 0; ww < w; ++ww) wpre += wtot[ww];
  int l0 = wpre + inc - sum2;   // LOCAL exclusive offset of node 2t within bucket
  int l1 = l0 + a0;
  int n0 = b * 512 + 2 * t, n1 = n0 + 1;
  if (n0 < NODES) { rowptr[n0] = bbase + l0; dinv[n0] = rsqrtf((float)a0 + 1.0f); }
  if (n1 < NODES) { rowptr[n1] = bbase + l1; dinv[n1] = rsqrtf((float)a1 + 1.0f); }
  cur[2 * t] = l0; cur[2 * t + 1] = l1;   // LOCAL positions -> stage in LDS
  __syncthreads();
  for (int i = t; i < cb; i += 256) {
    int pk = bp[i];
    int lp = atomicAdd(&cur[(pk >> 17) & 511], 1);
    stage[lp] = pk & 0x1FFFF;
  }
  __syncthreads();
  // fully coalesced csr write-out
  for (int i = t; i < cb; i += 256) csr[bbase + i] = stage[i];
}

// ---------- GEMM body: [N,128] fp32 @ [128,64] -> hs = bf16(x@W) (UNscaled) ----------
#define GEMM_SMEM (64 * 136 * 2)
__device__ __forceinline__ void gemm_body(char* smemraw, int tile0, const float* __restrict__ x,
                                          const float* __restrict__ W, short* __restrict__ hs) {
  constexpr int K = 128, KP = K + 8;
  short* wt = (short*)smemraw;  // W^T staged as bf16
  for (int idx = threadIdx.x; idx < K * 64; idx += 256) {
    int k = idx >> 6, n = idx & 63;
    wt[n * KP + k] = f2bf(W[idx]);
  }
  __syncthreads();
  int wid = threadIdx.x >> 6, lane = threadIdx.x & 63;
  int tile = tile0 + wid;
  if (tile * 16 >= NODES) return;
  int m = lane & 15, q = lane >> 4;

  short8 bfr[4][K / 32];
#pragma unroll
  for (int ct = 0; ct < 4; ++ct)
#pragma unroll
    for (int ks = 0; ks < K / 32; ++ks)
      bfr[ct][ks] = *reinterpret_cast<const short8*>(&wt[(ct * 16 + m) * KP + ks * 32 + q * 8]);

  floatx4 acc[4];
#pragma unroll
  for (int ct = 0; ct < 4; ++ct) acc[ct] = {0.f, 0.f, 0.f, 0.f};
  int r0 = tile * 16;
#pragma unroll
  for (int ks = 0; ks < K / 32; ++ks) {
    const float* xp = &x[(size_t)(r0 + m) * K + ks * 32 + q * 8];
    floatx4 a0 = *reinterpret_cast<const floatx4*>(xp);
    floatx4 a1 = *reinterpret_cast<const floatx4*>(xp + 4);
    short8 af;
#pragma unroll
    for (int j = 0; j < 4; ++j) { af[j] = f2bf(a0[j]); af[4 + j] = f2bf(a1[j]); }
#pragma unroll
    for (int ct = 0; ct < 4; ++ct)
      acc[ct] = __builtin_amdgcn_mfma_f32_16x16x32_bf16(af, bfr[ct][ks], acc[ct], 0, 0, 0);
  }
  // C/D: col = lane&15, row = (lane>>4)*4 + reg   [measured m89/m91]
#pragma unroll
  for (int ct = 0; ct < 4; ++ct)
#pragma unroll
    for (int r = 0; r < 4; ++r) {
      int row = r0 + q * 4 + r, col = ct * 16 + m;
      hs[row * 64 + col] = f2bf(acc[ct][r]);
    }
}

// ---------- ROUND-0 aggregation loop, weight-parameterized ----------
// acc = [PRESCALED ? 1 : dn]*hs[n] + sum_j w_j * hs[src_j],  w_j = PRESCALED?1:dinv[src_j]
template <bool PRESCALED>
__device__ __forceinline__ void do_agg(const uv4* __restrict__ hsv, const float* __restrict__ dinv,
                                       const int* __restrict__ csr, int n, int e0, int e1,
                                       int lane, float dn, float acc[8]) {
  int q = lane & 7, srcb = lane & 0x38;
  uv4 sv = hsv[(size_t)n * 8 + q];  // self row, features q*8..q*8+7
#pragma unroll
  for (int w = 0; w < 4; ++w) {
    float lo = bflo(sv[w]), hi = bfhi(sv[w]);
    if constexpr (PRESCALED) { acc[2 * w] = lo; acc[2 * w + 1] = hi; }
    else { acc[2 * w] = lo * dn; acc[2 * w + 1] = hi * dn; }
  }
  for (int base = e0; base < e1; base += 8) {
    int cnt = e1 - base;
    if (cnt > 8) cnt = 8;
    int a = base + (q < cnt ? q : 0);       // clamp: always valid in-row index
    int sidx = csr[a];
    float gq = 1.0f;
    if constexpr (!PRESCALED) gq = dinv[sidx];
    int s[8]; float wj[8];
#pragma unroll
    for (int j = 0; j < 8; ++j) {
      s[j] = __shfl(sidx, srcb | j, 64);
      if constexpr (!PRESCALED) {
        float bj = __shfl(gq, srcb | j, 64);
        wj[j] = (j < cnt) ? bj : 0.0f;
      } else {
        wj[j] = 1.0f;  // unused in PRESCALED accumulate below
      }
    }
    uv4 v[8];
#pragma unroll
    for (int j = 0; j < 8; ++j) v[j] = hsv[(size_t)s[j] * 8 + q];
    if constexpr (PRESCALED) {
      if (cnt == 8) {
#pragma unroll
        for (int j = 0; j < 8; ++j)
#pragma unroll
          for (int w = 0; w < 4; ++w) { acc[2 * w] += bflo(v[j][w]); acc[2 * w + 1] += bfhi(v[j][w]); }
      } else {
#pragma unroll
        for (int j = 0; j < 8; ++j)
          if (j < cnt)
#pragma unroll
            for (int w = 0; w < 4; ++w) { acc[2 * w] += bflo(v[j][w]); acc[2 * w + 1] += bfhi(v[j][w]); }
      }
    } else {
#pragma unroll
      for (int j = 0; j < 8; ++j)
#pragma unroll
        for (int w = 0; w < 4; ++w) {
          acc[2 * w]     += wj[j] * bflo(v[j][w]);
          acc[2 * w + 1] += wj[j] * bfhi(v[j][w]);
        }
    }
  }
}

// ---------- fused aggregate + bias + LN + GELU + next-layer GEMM ----------
// PRESCALED: hs rows already carry dinv[src]; else gather dinv per edge.
// W staged IN-KERNEL from fp32 (round-0 entry code: restores the VGPR-52-class schedule)
// writes hsn = dinv ⊙ (u @ W)  [row-scale commute]
template <bool PRESCALED>
__global__ __launch_bounds__(256) void k_aggg(const short* __restrict__ hs,
                                              const float* __restrict__ dinv,
                                              const int* __restrict__ rowptr,
                                              const int* __restrict__ csr,
                                              const float* __restrict__ bias,
                                              const float* __restrict__ gam,
                                              const float* __restrict__ bet,
                                              const float* __restrict__ W,   // next-layer W fp32 [64x64]
                                              short* __restrict__ hsn) {
  __shared__ __align__(16) short wt[64 * 72];  // W^T bf16
  __shared__ __align__(16) short ut[32 * 72];  // (dinv*u) tile bf16
  int t = threadIdx.x;
  for (int idx = t; idx < 4096; idx += 256) {
    int k = idx >> 6, n = idx & 63;
    wt[n * 72 + k] = f2bf(W[idx]);
  }
  const uv4* hsv = (const uv4*)hs;
  int lane = t & 63, wid = t >> 6;
  int g = lane >> 3, q = lane & 7;
  int nb0 = blockIdx.x * 32;
  int r = wid * 8 + g;                      // row in 32-node tile
  int n = nb0 + r;                          // grid 3125 exact -> always valid
  int e0 = rowptr[n], e1 = rowptr[n + 1];
  float dn = dinv[n];
  float acc[8];
  do_agg<PRESCALED>(hsv, dinv, csr, n, e0, e1, lane, dn, acc);

  const floatx4* bi4 = (const floatx4*)bias;
  floatx4 b0 = bi4[q * 2], b1 = bi4[q * 2 + 1];
#pragma unroll
  for (int f = 0; f < 4; ++f) { acc[f] = acc[f] * dn + b0[f]; acc[f + 4] = acc[f + 4] * dn + b1[f]; }

  float lsum = 0.f;
#pragma unroll
  for (int f = 0; f < 8; ++f) lsum += acc[f];
  float mu = gsum8(lsum) * (1.0f / 64.0f);
  float d[8], lvar = 0.f;
#pragma unroll
  for (int f = 0; f < 8; ++f) { d[f] = acc[f] - mu; lvar += d[f] * d[f]; }
  float rs = rsqrtf(gsum8(lvar) * (1.0f / 64.0f) + 1e-5f);
  const floatx4* gm4 = (const floatx4*)gam;
  const floatx4* bt4 = (const floatx4*)bet;
  floatx4 g0 = gm4[q * 2], g1 = gm4[q * 2 + 1];
  floatx4 t0 = bt4[q * 2], t1 = bt4[q * 2 + 1];
  short8 us;
#pragma unroll
  for (int f = 0; f < 8; ++f) {
    float gv = (f < 4) ? g0[f] : g1[f - 4];
    float tv = (f < 4) ? t0[f] : t1[f - 4];
    float vv = d[f] * rs * gv + tv;
    float u = 0.5f * vv * (1.0f + erff(vv * 0.70710678118654752f));  // exact GELU
    us[f] = f2bf(u * dn);                   // prescale for next layer (commute)
  }
  *reinterpret_cast<short8*>(&ut[r * 72 + q * 8]) = us;
  __syncthreads();

  // in-block GEMM: 32x64 tile @ W (64x64) -> hsn rows nb0..nb0+31
  int m = lane & 15, q2 = lane >> 4;
  int tile = wid >> 1, cb = (wid & 1) * 2;  // wave -> (row-tile, ct pair)
  short8 bfr[2][2];
#pragma unroll
  for (int ct = 0; ct < 2; ++ct)
#pragma unroll
    for (int ks = 0; ks < 2; ++ks)
      bfr[ct][ks] = *reinterpret_cast<const short8*>(&wt[((cb + ct) * 16 + m) * 72 + ks * 32 + q2 * 8]);
  floatx4 ac[2];
#pragma unroll
  for (int ct = 0; ct < 2; ++ct) ac[ct] = {0.f, 0.f, 0.f, 0.f};
#pragma unroll
  for (int ks = 0; ks < 2; ++ks) {
    short8 af = *reinterpret_cast<const short8*>(&ut[(tile * 16 + m) * 72 + ks * 32 + q2 * 8]);
#pragma unroll
    for (int ct = 0; ct < 2; ++ct)
      ac[ct] = __builtin_amdgcn_mfma_f32_16x16x32_bf16(af, bfr[ct][ks], ac[ct], 0, 0, 0);
  }
#pragma unroll
  for (int ct = 0; ct < 2; ++ct)
#pragma unroll
    for (int rr = 0; rr < 4; ++rr) {
      int row = nb0 + tile * 16 + q2 * 4 + rr, col = (cb + ct) * 16 + m;
      hsn[row * 64 + col] = f2bf(ac[ct][rr]);
    }
}

// ---------- final layer: aggregate + bias + LN + GELU + head ----------
__global__ __launch_bounds__(256) void k_agg_fin(const short* __restrict__ hs,
                                                 const float* __restrict__ dinv,
                                                 const int* __restrict__ rowptr,
                                                 const int* __restrict__ csr,
                                                 const float* __restrict__ bias,
                                                 const float* __restrict__ gam,
                                                 const float* __restrict__ bet,
                                                 const float* __restrict__ Wh,
                                                 const float* __restrict__ bh,
                                                 float* __restrict__ out) {
  const uv4* hsv = (const uv4*)hs;
  int lane = threadIdx.x & 63, wid = threadIdx.x >> 6;
  int g = lane >> 3, q = lane & 7;
  int n = blockIdx.x * 32 + wid * 8 + g;
  int e0 = rowptr[n], e1 = rowptr[n + 1];
  float dn = dinv[n];
  float acc[8];
  do_agg<true>(hsv, dinv, csr, n, e0, e1, lane, dn, acc);
  const floatx4* bi4 = (const floatx4*)bias;
  floatx4 b0 = bi4[q * 2], b1 = bi4[q * 2 + 1];
#pragma unroll
  for (int f = 0; f < 4; ++f) { acc[f] = acc[f] * dn + b0[f]; acc[f + 4] = acc[f + 4] * dn + b1[f]; }
  float lsum = 0.f;
#pragma unroll
  for (int f = 0; f < 8; ++f) lsum += acc[f];
  float mu = gsum8(lsum) * (1.0f / 64.0f);
  float d[8], lvar = 0.f;
#pragma unroll
  for (int f = 0; f < 8; ++f) { d[f] = acc[f] - mu; lvar += d[f] * d[f]; }
  float rs = rsqrtf(gsum8(lvar) * (1.0f / 64.0f) + 1e-5f);
  const floatx4* gm4 = (const floatx4*)gam;
  const floatx4* bt4 = (const floatx4*)bet;
  floatx4 g0 = gm4[q * 2], g1 = gm4[q * 2 + 1];
  floatx4 t0 = bt4[q * 2], t1 = bt4[q * 2 + 1];
  const floatx4* wh4 = (const floatx4*)Wh;
  floatx4 w0 = wh4[q * 2], w1 = wh4[q * 2 + 1];
  float lp = 0.f;
#pragma unroll
  for (int f = 0; f < 8; ++f) {
    float gv = (f < 4) ? g0[f] : g1[f - 4];
    float tv = (f < 4) ? t0[f] : t1[f - 4];
    float wv = (f < 4) ? w0[f] : w1[f - 4];
    float vv = d[f] * rs * gv + tv;
    float u = 0.5f * vv * (1.0f + erff(vv * 0.70710678118654752f));
    lp += u * wv;
  }
  float p = gsum8(lp);
  if (q == 0) out[n] = p + bh[0];
}

// ---------- fused dispatch wrappers ----------
// dispatch 1: binning (391) || FULL gemm (1563)
__global__ __launch_bounds__(256) void k_pre1(const int* __restrict__ src, const int* __restrict__ dst,
                                              int* __restrict__ bins, int* __restrict__ gcur,
                                              const float* __restrict__ x, const float* __restrict__ W1,
                                              short* __restrict__ hs) {
  __shared__ __align__(16) char smem[BIN_SMEM];  // 24576 >= GEMM_SMEM 17408
  int b = blockIdx.x;
  if (b < BINB) bin_body(smem, b, src, dst, bins, gcur);
  else gemm_body(smem, (b - BINB) * 4, x, W1, hs);
}

// dispatch 2: csr fill (196 blocks, big LDS stage)
__global__ __launch_bounds__(256) void k_pre2(const int* __restrict__ bins, const int* __restrict__ gcur,
                                              int* __restrict__ rowptr, float* __restrict__ dinv,
                                              int* __restrict__ csr) {
  __shared__ __align__(16) char smem[FILL_SMEM];
  fill_body(smem, blockIdx.x, bins, gcur, rowptr, dinv, csr);
}

// standalone fallback wrappers (ws too small to un-alias bins)
__global__ __launch_bounds__(256) void k_bin2(const int* src, const int* dst, int* bins, int* gcur) {
  __shared__ __align__(16) char smem[BIN_SMEM];
  bin_body(smem, blockIdx.x, src, dst, bins, gcur);
}
__global__ __launch_bounds__(256) void k_fillb2(const int* bins, const int* gcur, int* rowptr,
                                                float* dinv, int* csr) {
  __shared__ __align__(16) char smem[FILL_SMEM];
  fill_body(smem, blockIdx.x, bins, gcur, rowptr, dinv, csr);
}
__global__ __launch_bounds__(256) void k_gemm(const float* x, const float* W, short* hs) {
  __shared__ __align__(16) char smem[GEMM_SMEM];
  gemm_body(smem, blockIdx.x * 4, x, W, hs);
}

extern "C" void kernel_launch(void* const* d_in, const int* in_sizes, int n_in,
                              void* d_out, int out_size, void* d_ws, size_t ws_size,
                              hipStream_t stream) {
  const float* x  = (const float*)d_in[0];
  const int* ei   = (const int*)d_in[1];
  const float* W1 = (const float*)d_in[2];
  const float* b1 = (const float*)d_in[3];
  const float* g1 = (const float*)d_in[4];
  const float* be1= (const float*)d_in[5];
  const float* W2 = (const float*)d_in[6];
  const float* b2 = (const float*)d_in[7];
  const float* g2 = (const float*)d_in[8];
  const float* be2= (const float*)d_in[9];
  const float* W3 = (const float*)d_in[10];
  const float* b3 = (const float*)d_in[11];
  const float* g3 = (const float*)d_in[12];
  const float* be3= (const float*)d_in[13];
  const float* Wh = (const float*)d_in[14];
  const float* bh = (const float*)d_in[15];
  const int* srcp = ei;
  const int* dstp = ei + EDGES;

  char* ws = (char*)d_ws;
  size_t off = 0;
  auto take = [&](size_t bytes) {
    char* p = ws + off;
    off = (off + bytes + 255) & ~(size_t)255;
    return p;
  };
  float* dinv = (float*)take((size_t)NODES * 4);
  int* rowptr = (int*)take((size_t)(NODES + 1) * 4);
  int* csr    = (int*)take((size_t)EDGES * 4);
  short* hs_a = (short*)take((size_t)NODES * 64 * 2);   // 12.8 MB
  short* hs_b = (short*)take((size_t)NODES * 64 * 2);   // 12.8 MB

  size_t bins_sz = (size_t)NBUCK * BCAP2 * 4;           // 9.63 MB
  bool overlap = (ws_size >= off + bins_sz + 4096);
  int* bins; int* gcur;
  if (overlap) {
    bins = (int*)take(bins_sz);
    gcur = (int*)take((size_t)NBUCK * 4);
  } else {
    // fall back to aliasing (bins consumed by fill before any GEMM writes hs)
    bins = (int*)hs_a;
    gcur = (int*)hs_b;
  }

  (void)hipMemsetAsync(gcur, 0, (size_t)NBUCK * 4, stream);
  if (overlap) {
    k_pre1<<<BINB + GEMMB, 256, 0, stream>>>(srcp, dstp, bins, gcur, x, W1, hs_a);
    k_pre2<<<NBUCK, 256, 0, stream>>>(bins, gcur, rowptr, dinv, csr);
  } else {
    k_bin2<<<BINB, 256, 0, stream>>>(srcp, dstp, bins, gcur);
    k_fillb2<<<NBUCK, 256, 0, stream>>>(bins, gcur, rowptr, dinv, csr);
    k_gemm<<<GEMMB, 256, 0, stream>>>(x, W1, hs_a);
  }
  // layer 1: hs_a is UNscaled -> gather dinv[src] per edge (weights in agg)
  k_aggg<false><<<NODES / 32, 256, 0, stream>>>(hs_a, dinv, rowptr, csr, b1, g1, be1, W2, hs_b);
  // layers 2/3: producer prescaled rows by dinv
  k_aggg<true><<<NODES / 32, 256, 0, stream>>>(hs_b, dinv, rowptr, csr, b2, g2, be2, W3, hs_a);
  k_agg_fin<<<NODES / 32, 256, 0, stream>>>(hs_a, dinv, rowptr, csr, b3, g3, be3, Wh, bh, (float*)d_out);
}